// Round 1
// 773.670 us; speedup vs baseline: 1.2448x; 1.2448x over previous
//
#include <hip/hip_runtime.h>
#include <cstdint>
#include <cstddef>

#define B 32
#define H 12
#define L 512
#define D 768
#define KSEL 255

// workspace byte offsets -- only imp needs memset-zero now (sent/y zeroed in-kernel)
#define OFF_IMP   0          // float[B*L]      65536  (memset target)
#define MEMSET_BYTES 65536
#define OFF_SENT  65536      // float[B*D]      98304  (zeroed in k_prep)
#define OFF_Y     163840     // float[B*H*D]  1179648  (zeroed in k_logits)
#define OFF_ATT   1343488    // float[B*L]      65536
#define OFF_Q     1409024    // float[B*D]      98304
#define OFF_A     1507328    // float[B*H*D]  1179648
#define OFF_CB    2686976    // float[B*H]       1536
#define OFF_LG    2688512    // float[B*H*L]   786432
#define OFF_SEL   3474944    // int[B*KSEL]     32640
#define OFF_CTX   3507584    // float[B*D]      98304

// ---- 1. imp[b,j] = sum_{h,l} amf[l]*sas[b,h,l,j]  (fp32; boundary gap >> atomic noise) ----
__global__ __launch_bounds__(128) void k_imp(const float* __restrict__ sas,
                                             const float* __restrict__ am,
                                             float* __restrict__ imp) {
  const int b = blockIdx.x, h = blockIdx.y, ch = blockIdx.z;  // ch: 4 chunks of 128 rows
  const int t = threadIdx.x;                                  // 128 threads, float4 each
  const float* base = sas + (((size_t)(b * H + h)) * L + (size_t)ch * 128) * L;
  const float* amb = am + b * L + ch * 128;
  float a0 = 0, a1 = 0, a2 = 0, a3 = 0;
#pragma unroll 8
  for (int l = 0; l < 128; ++l) {
    const float m = (amb[l] > -10.0f) ? 1.0f : 0.0f;
    const float4 v = reinterpret_cast<const float4*>(base + (size_t)l * L)[t];
    a0 += m * v.x;
    a1 += m * v.y;
    a2 += m * v.z;
    a3 += m * v.w;
  }
  float* ip = imp + b * L + t * 4;
  atomicAdd(ip + 0, a0);
  atomicAdd(ip + 1, a1);
  atomicAdd(ip + 2, a2);
  atomicAdd(ip + 3, a3);
}

// ---- 2. merged: att softmax + top-255 select (rank + scan) + mask/tome outputs ----
//         also zeroes sent[b,:] for k_sent's atomics (replaces big memset)
__global__ __launch_bounds__(512) void k_prep(const float* __restrict__ am,
                                              const float* __restrict__ imp,
                                              float* __restrict__ att,
                                              int* __restrict__ sel,
                                              float* __restrict__ out_mask,
                                              float* __restrict__ out_tome,
                                              float* __restrict__ sent) {
  const int b = blockIdx.x, l = threadIdx.x;
  __shared__ float r1[8], r2[8];
  __shared__ float v[512];
  __shared__ int sc[512];
  // zero sent (runs strictly before k_sent)
  sent[b * D + l] = 0.0f;
  if (l < D - 512) sent[b * D + 512 + l] = 0.0f;
  const float aml = am[b * L + l];
  // --- softmax(am) -> att ---
  float m = aml;
#pragma unroll
  for (int o = 32; o; o >>= 1) m = fmaxf(m, __shfl_down(m, o));
  if ((l & 63) == 0) r1[l >> 6] = m;
  __syncthreads();
  if (l == 0) {
    float mm = r1[0];
    for (int i = 1; i < 8; ++i) mm = fmaxf(mm, r1[i]);
    r1[0] = mm;
  }
  __syncthreads();
  const float M = r1[0];
  const float e = expf(aml - M);
  float s = e;
#pragma unroll
  for (int o = 32; o; o >>= 1) s += __shfl_down(s, o);
  if ((l & 63) == 0) r2[l >> 6] = s;
  __syncthreads();
  if (l == 0) {
    float ss = 0.f;
    for (int i = 0; i < 8; ++i) ss += r2[i];
    r2[0] = ss;
  }
  __syncthreads();
  att[b * L + l] = e / r2[0];
  // --- selection: rank with index tie-break, then index-order compaction via scan ---
  float val;
  if (l == 0)
    val = INFINITY;
  else
    val = (aml > -10.0f) ? imp[b * L + l] : 0.0f;
  v[l] = val;
  __syncthreads();
  int r = 0;
  for (int t = 0; t < 512; ++t) {
    const float vt = v[t];
    r += (vt > val) || (vt == val && t < l);
  }
  const int f = (r < KSEL) ? 1 : 0;
  sc[l] = f;
  __syncthreads();
  for (int off = 1; off < 512; off <<= 1) {
    const int add = (l >= off) ? sc[l - off] : 0;
    __syncthreads();
    sc[l] += add;
    __syncthreads();
  }
  if (f) {
    const int pos = sc[l] - 1;  // 0..254
    sel[b * KSEL + pos] = l;
    out_mask[b * 256 + pos] = aml;
  }
  if (l == 0) out_mask[b * 256 + 255] = 0.0f;
  if (l < 256) out_tome[b * 256 + l] = 1.0f;
}

// ---- 3. gather preserved rows (4 rows per block) ----
__global__ __launch_bounds__(256) void k_gather(const float* __restrict__ hs,
                                                const int* __restrict__ sel,
                                                float* __restrict__ out_tok) {
  const int row = blockIdx.x * 4 + (threadIdx.x >> 6);  // B*KSEL rows
  const int lane = threadIdx.x & 63;
  const int b = row / KSEL, p = row % KSEL;
  const int j = sel[row];
  const float4* src = reinterpret_cast<const float4*>(hs + ((size_t)b * L + j) * D);
  float4* dst = reinterpret_cast<float4*>(out_tok + ((size_t)b * 256 + p) * D);
#pragma unroll
  for (int i = 0; i < 3; ++i) dst[lane + 64 * i] = src[lane + 64 * i];
}

// ---- 4. sentences[b,d] = sum_l att[b,l]*hs[b,l,d] ----
__global__ __launch_bounds__(768) void k_sent(const float* __restrict__ hs,
                                              const float* __restrict__ att,
                                              float* __restrict__ sent) {
  const int b = blockIdx.x, c = blockIdx.y, t = threadIdx.x;  // c: 8 chunks of 64 rows
  __shared__ float a[64];
  if (t < 64) a[t] = att[b * L + c * 64 + t];
  __syncthreads();
  const float* h0 = hs + ((size_t)b * L + c * 64) * D;
  float acc = 0.f;
  for (int l = 0; l < 64; ++l) acc += a[l] * h0[(size_t)l * D + t];
  atomicAdd(&sent[b * D + t], acc);
}

// ---- 5. q[b,u] = bq[u] + sent@Wq ; fused cb[b,h] = bk_h . q_h ----
//         wave = one b; 4 independent accumulators break the serial FMA chain
__global__ __launch_bounds__(512) void k_q(const float* __restrict__ sent,
                                           const float* __restrict__ Wq,
                                           const float* __restrict__ bq,
                                           const float* __restrict__ bk,
                                           float* __restrict__ qg,
                                           float* __restrict__ cbg) {
  const int h = blockIdx.x;                              // 12 head-aligned 64-col chunks
  const int b = blockIdx.y * 8 + (threadIdx.x >> 6);     // 4 groups of 8 b, wave = b
  const int ul = threadIdx.x & 63;
  const int u = h * 64 + ul;
  const float* sb = sent + b * D;
  float a0 = 0.f, a1 = 0.f, a2 = 0.f, a3 = 0.f;
#pragma unroll 4
  for (int d = 0; d < D; d += 4) {
    a0 += sb[d + 0] * Wq[(size_t)(d + 0) * D + u];
    a1 += sb[d + 1] * Wq[(size_t)(d + 1) * D + u];
    a2 += sb[d + 2] * Wq[(size_t)(d + 2) * D + u];
    a3 += sb[d + 3] * Wq[(size_t)(d + 3) * D + u];
  }
  const float acc = bq[u] + ((a0 + a1) + (a2 + a3));
  qg[b * D + u] = acc;
  float v = bk[u] * acc;  // wave = one (b); reduce over ul
#pragma unroll
  for (int o = 32; o; o >>= 1) v += __shfl_down(v, o);
  if (ul == 0) cbg[b * H + h] = v;
}

// ---- 6. A[b,h,d] = sum_c Wk[d,h*64+c]*q[b,h*64+c] ----
__global__ __launch_bounds__(1024) void k_A(const float* __restrict__ qg,
                                            const float* __restrict__ Wk,
                                            float* __restrict__ Ag) {
  const int h = blockIdx.x;   // 12
  const int dc = blockIdx.y;  // 12 chunks of 64 d
  const int dl = threadIdx.x & 63;
  const int bl = threadIdx.x >> 6;
  __shared__ float tile[64][65];  // Wk[dc*64+r, h*64+c], padded
  for (int i = threadIdx.x; i < 4096; i += 1024) {
    const int rr = i >> 6, cc = i & 63;
    tile[rr][cc] = Wk[(size_t)(dc * 64 + rr) * D + h * 64 + cc];
  }
  __syncthreads();
  const int d = dc * 64 + dl;
#pragma unroll
  for (int half = 0; half < 2; ++half) {
    const int b = half * 16 + bl;
    const float* qh = qg + b * D + h * 64;
    float acc = 0.f;
#pragma unroll
    for (int c = 0; c < 64; ++c) acc += tile[dl][c] * qh[c];
    Ag[((size_t)b * H + h) * D + d] = acc;
  }
}

// ---- 7. logits[b,h,l] = (x_l . A[b,h,:] + cb[b,h]) / 8 ; ch==0 blocks zero y ----
__global__ __launch_bounds__(256) void k_logits(const float* __restrict__ hs,
                                                const float* __restrict__ Ag,
                                                const float* __restrict__ cbg,
                                                float* __restrict__ lg,
                                                float* __restrict__ y) {
  const int b = blockIdx.x, ch = blockIdx.y;  // 16 chunks of 32 rows
  if (ch == 0) {  // zero y[b,:,:] for k_ysoft's atomics (runs strictly before)
    for (int i = threadIdx.x; i < H * D; i += 256) y[(size_t)b * H * D + i] = 0.0f;
  }
  __shared__ float A[H * D];                  // 36 KB
  for (int i = threadIdx.x; i < H * D; i += 256) A[i] = Ag[(size_t)b * H * D + i];
  __syncthreads();
  const int wave = threadIdx.x >> 6, lane = threadIdx.x & 63;
  const float* h0 = hs + (size_t)b * L * D;
  for (int li = 0; li < 8; ++li) {
    const int l = ch * 32 + li * 4 + wave;
    const float* xr = h0 + (size_t)l * D;
    float xv[12];
#pragma unroll
    for (int k = 0; k < 12; ++k) xv[k] = xr[lane + 64 * k];
#pragma unroll
    for (int h = 0; h < H; ++h) {
      float a = 0.f;
#pragma unroll
      for (int k = 0; k < 12; ++k) a += xv[k] * A[h * D + lane + 64 * k];
#pragma unroll
      for (int o = 32; o; o >>= 1) a += __shfl_down(a, o);
      if (lane == 0) lg[((size_t)b * H + h) * L + l] = (a + cbg[b * H + h]) * 0.125f;
    }
  }
}

// ---- 8. merged softmax + y: y[b,h,d] = sum_l softmax(lg)[b,h,l]*x[b,l,d] ----
//         8 chunks of 64 l -> 256 blocks (full machine; was 128)
__global__ __launch_bounds__(768) void k_ysoft(const float* __restrict__ hs,
                                               const float* __restrict__ lg,
                                               const float* __restrict__ am,
                                               float* __restrict__ y) {
  const int b = blockIdx.x, c = blockIdx.y, t = threadIdx.x;  // c: 8 chunks of 64 l
  __shared__ float wl[H * L];   // 24 KB raw (masked) logits
  __shared__ float Ms[H], Is[H];
  __shared__ float wn[H * 64];  // normalized weights for this chunk
  for (int i = t; i < H * L; i += 768) {
    const int l = i & (L - 1);
    const float aml = am[b * L + l];
    wl[i] = (aml < -10.0f) ? -INFINITY : lg[(size_t)b * H * L + i];
  }
  __syncthreads();
  {  // wave g == head h (768 = 12 waves of 64)
    const int h = t >> 6, lane = t & 63;
    float m = -INFINITY;
#pragma unroll
    for (int k = 0; k < 8; ++k) m = fmaxf(m, wl[h * L + lane + 64 * k]);
#pragma unroll
    for (int o = 32; o; o >>= 1) m = fmaxf(m, __shfl_xor(m, o));
    float s = 0.f;
#pragma unroll
    for (int k = 0; k < 8; ++k) s += expf(wl[h * L + lane + 64 * k] - m);
#pragma unroll
    for (int o = 32; o; o >>= 1) s += __shfl_xor(s, o);
    if (lane == 0) { Ms[h] = m; Is[h] = 1.0f / s; }
  }
  __syncthreads();
  {  // one pass: 768 threads cover H*64 exactly
    const int h = t >> 6, l = t & 63;
    wn[t] = expf(wl[h * L + c * 64 + l] - Ms[h]) * Is[h];
  }
  __syncthreads();
  const float* h0 = hs + ((size_t)b * L + c * 64) * D;
  float acc[12];
#pragma unroll
  for (int h = 0; h < 12; ++h) acc[h] = 0.f;
  for (int l = 0; l < 64; ++l) {
    const float x = h0[(size_t)l * D + t];
#pragma unroll
    for (int h = 0; h < 12; ++h) acc[h] += wn[h * 64 + l] * x;
  }
#pragma unroll
  for (int h = 0; h < 12; ++h) atomicAdd(&y[((size_t)b * H + h) * D + t], acc[h]);
}

// ---- 9. ctx[b,h*64+c] = bv + sum_d y[b,h,d]*Wv[d,h*64+c] ----
__global__ __launch_bounds__(512) void k_ctx(const float* __restrict__ y,
                                             const float* __restrict__ Wv,
                                             const float* __restrict__ bv,
                                             float* __restrict__ ctx) {
  const int h = blockIdx.x;
  const int b = blockIdx.y * 8 + (threadIdx.x >> 6);  // wave = one b
  const int c = threadIdx.x & 63;
  const float* yb = y + ((size_t)b * H + h) * D;
  float a0 = 0.f, a1 = 0.f, a2 = 0.f, a3 = 0.f;
#pragma unroll 4
  for (int d = 0; d < D; d += 4) {
    a0 += yb[d + 0] * Wv[(size_t)(d + 0) * D + h * 64 + c];
    a1 += yb[d + 1] * Wv[(size_t)(d + 1) * D + h * 64 + c];
    a2 += yb[d + 2] * Wv[(size_t)(d + 2) * D + h * 64 + c];
    a3 += yb[d + 3] * Wv[(size_t)(d + 3) * D + h * 64 + c];
  }
  ctx[b * D + h * 64 + c] = bv[h * 64 + c] + ((a0 + a1) + (a2 + a3));
}

// ---- 10. new_token[b,d'] = bo + ctx@Wo -> final_token row 255 ----
__global__ __launch_bounds__(512) void k_out(const float* __restrict__ ctx,
                                             const float* __restrict__ Wo,
                                             const float* __restrict__ bo,
                                             float* __restrict__ out_tok) {
  const int dc = blockIdx.x;
  const int b = blockIdx.y * 8 + (threadIdx.x >> 6);  // wave = one b
  const int dl = threadIdx.x & 63;
  const int dd = dc * 64 + dl;
  const float* cb = ctx + b * D;
  float a0 = 0.f, a1 = 0.f, a2 = 0.f, a3 = 0.f;
#pragma unroll 4
  for (int u = 0; u < D; u += 4) {
    a0 += cb[u + 0] * Wo[(size_t)(u + 0) * D + dd];
    a1 += cb[u + 1] * Wo[(size_t)(u + 1) * D + dd];
    a2 += cb[u + 2] * Wo[(size_t)(u + 2) * D + dd];
    a3 += cb[u + 3] * Wo[(size_t)(u + 3) * D + dd];
  }
  out_tok[((size_t)b * 256 + 255) * D + dd] = bo[dd] + ((a0 + a1) + (a2 + a3));
}

extern "C" void kernel_launch(void* const* d_in, const int* in_sizes, int n_in,
                              void* d_out, int out_size, void* d_ws, size_t ws_size,
                              hipStream_t stream) {
  const float* hs = (const float*)d_in[0];
  const float* am = (const float*)d_in[1];
  const float* sas = (const float*)d_in[2];
  const float* Wq = (const float*)d_in[3];
  const float* bq = (const float*)d_in[4];
  const float* Wk = (const float*)d_in[5];
  const float* bk = (const float*)d_in[6];
  const float* Wv = (const float*)d_in[7];
  const float* bv = (const float*)d_in[8];
  const float* Wo = (const float*)d_in[9];
  const float* bo = (const float*)d_in[10];

  float* out_tok = (float*)d_out;                   // [B,256,D]
  float* out_mask = out_tok + (size_t)B * 256 * D;  // [B,1,1,256]
  float* out_tome = out_mask + (size_t)B * 256;     // [B,256,1]

  char* ws = (char*)d_ws;
  float* imp = (float*)(ws + OFF_IMP);
  float* sent = (float*)(ws + OFF_SENT);
  float* yg = (float*)(ws + OFF_Y);
  float* att = (float*)(ws + OFF_ATT);
  float* qg = (float*)(ws + OFF_Q);
  float* Ag = (float*)(ws + OFF_A);
  float* cbg = (float*)(ws + OFF_CB);
  float* lg = (float*)(ws + OFF_LG);
  int* sel = (int*)(ws + OFF_SEL);
  float* ctx = (float*)(ws + OFF_CTX);

  hipMemsetAsync(d_ws, 0, MEMSET_BYTES, stream);

  k_imp<<<dim3(B, H, 4), 128, 0, stream>>>(sas, am, imp);
  k_prep<<<B, 512, 0, stream>>>(am, imp, att, sel, out_mask, out_tome, sent);
  k_gather<<<(B * KSEL) / 4, 256, 0, stream>>>(hs, sel, out_tok);
  k_sent<<<dim3(B, 8), 768, 0, stream>>>(hs, att, sent);
  k_q<<<dim3(12, 4), 512, 0, stream>>>(sent, Wq, bq, bk, qg, cbg);
  k_A<<<dim3(12, 12), 1024, 0, stream>>>(qg, Wk, Ag);
  k_logits<<<dim3(B, 16), 256, 0, stream>>>(hs, Ag, cbg, lg, yg);
  k_ysoft<<<dim3(B, 8), 768, 0, stream>>>(hs, lg, am, yg);
  k_ctx<<<dim3(12, 4), 512, 0, stream>>>(yg, Wv, bv, ctx);
  k_out<<<dim3(12, 4), 512, 0, stream>>>(ctx, Wo, bo, out_tok);
}

// Round 2
// 751.255 us; speedup vs baseline: 1.2819x; 1.0298x over previous
//
#include <hip/hip_runtime.h>
#include <cstdint>
#include <cstddef>

#define B 32
#define H 12
#define L 512
#define D 768
#define KSEL 255

// workspace byte offsets -- only imp needs memset-zero (sent/y zeroed in-kernel)
#define OFF_IMP   0          // float[B*L]      65536  (memset target)
#define MEMSET_BYTES 65536
#define OFF_ATT   65536      // float[B*L]      65536
#define OFF_SENT  131072     // float[B*D]      98304  (zeroed in F1 att role)
#define OFF_Q     229376     // float[B*D]      98304
#define OFF_CB    327680     // float[B*H]       1536
#define OFF_A     329216     // float[B*H*D]  1179648
#define OFF_LG    1508864    // float[B*H*L]   786432
#define OFF_SEL   2295296    // int[B*KSEL]     32640
#define OFF_Y     2327936    // float[B*H*D]  1179648  (zeroed in F3)
#define OFF_CTX   3507584    // float[B*D]      98304

// ---- imp slice: vb in [0,1536) = (b,h,ch); 512 thr = 4 row-groups of 128 lanes ----
__device__ __forceinline__ void imp_slice(const float* __restrict__ sas,
                                          const float* __restrict__ am,
                                          float* __restrict__ imp,
                                          int vb, int t, float4* red) {
  const int b = vb / 48, r = vb % 48, h = r >> 2, ch = r & 3;
  const int g = t >> 7, c = t & 127;
  const int row0 = ch * 128 + g * 32;
  const float* base = sas + (((size_t)(b * H + h)) * L + row0) * L;
  const float* amb = am + b * L + row0;
  float a0 = 0, a1 = 0, a2 = 0, a3 = 0;
#pragma unroll 8
  for (int l = 0; l < 32; ++l) {
    const float m = (amb[l] > -10.0f) ? 1.0f : 0.0f;
    const float4 v = reinterpret_cast<const float4*>(base + (size_t)l * L)[c];
    a0 += m * v.x;
    a1 += m * v.y;
    a2 += m * v.z;
    a3 += m * v.w;
  }
  red[g * 128 + c] = make_float4(a0, a1, a2, a3);
  __syncthreads();
  if (g == 0) {
    const float4 r0 = red[c], r1 = red[128 + c], r2 = red[256 + c], r3 = red[384 + c];
    float* ip = imp + b * L + c * 4;
    atomicAdd(ip + 0, r0.x + r1.x + r2.x + r3.x);
    atomicAdd(ip + 1, r0.y + r1.y + r2.y + r3.y);
    atomicAdd(ip + 2, r0.z + r1.z + r2.z + r3.z);
    atomicAdd(ip + 3, r0.w + r1.w + r2.w + r3.w);
  }
}

// ---- F1: imp slice 0  ||  att=softmax(am) + zero sent (blocks 0..31) ----
__global__ __launch_bounds__(512) void k_f1(const float* __restrict__ sas,
                                            const float* __restrict__ am,
                                            float* __restrict__ imp,
                                            float* __restrict__ att,
                                            float* __restrict__ sent) {
  __shared__ float4 red[512];
  __shared__ float r1[8], r2[8];
  const int bid = blockIdx.x, t = threadIdx.x;
  imp_slice(sas, am, imp, bid, t, red);
  if (bid < B) {
    const int b = bid, l = t;
    sent[b * D + l] = 0.0f;
    if (l < D - 512) sent[b * D + 512 + l] = 0.0f;
    const float aml = am[b * L + l];
    float m = aml;
#pragma unroll
    for (int o = 32; o; o >>= 1) m = fmaxf(m, __shfl_down(m, o));
    if ((l & 63) == 0) r1[l >> 6] = m;
    __syncthreads();
    if (l == 0) {
      float mm = r1[0];
      for (int i = 1; i < 8; ++i) mm = fmaxf(mm, r1[i]);
      r1[0] = mm;
    }
    __syncthreads();
    const float M = r1[0];
    const float e = expf(aml - M);
    float s = e;
#pragma unroll
    for (int o = 32; o; o >>= 1) s += __shfl_down(s, o);
    if ((l & 63) == 0) r2[l >> 6] = s;
    __syncthreads();
    if (l == 0) {
      float ss = 0.f;
      for (int i = 0; i < 8; ++i) ss += r2[i];
      r2[0] = ss;
    }
    __syncthreads();
    att[b * L + l] = e / r2[0];
  }
}

// ---- F2: imp slice 1  ||  sent (blocks 0..255: vb=(b, c-of-8), float4 rows) ----
__global__ __launch_bounds__(512) void k_f2(const float* __restrict__ sas,
                                            const float* __restrict__ am,
                                            const float* __restrict__ hs,
                                            const float* __restrict__ att,
                                            float* __restrict__ imp,
                                            float* __restrict__ sent) {
  __shared__ float4 red[512];
  __shared__ float a[64];
  __shared__ float4 red2[8][192];  // 24 KB
  const int bid = blockIdx.x, t = threadIdx.x;
  imp_slice(sas, am, imp, 512 + bid, t, red);
  if (bid < 256) {
    const int b = bid >> 3, c = bid & 7;
    const int w = t >> 6, lane = t & 63;
    if (t < 64) a[t] = att[b * L + c * 64 + t];
    __syncthreads();
    const float* h0 = hs + ((size_t)b * L + c * 64) * D;
    float4 s0 = {0, 0, 0, 0}, s1 = {0, 0, 0, 0}, s2 = {0, 0, 0, 0};
    for (int l = w; l < 64; l += 8) {
      const float al = a[l];
      const float4* row = reinterpret_cast<const float4*>(h0 + (size_t)l * D);
      const float4 v0 = row[lane], v1 = row[lane + 64], v2 = row[lane + 128];
      s0.x += al * v0.x; s0.y += al * v0.y; s0.z += al * v0.z; s0.w += al * v0.w;
      s1.x += al * v1.x; s1.y += al * v1.y; s1.z += al * v1.z; s1.w += al * v1.w;
      s2.x += al * v2.x; s2.y += al * v2.y; s2.z += al * v2.z; s2.w += al * v2.w;
    }
    red2[w][lane] = s0;
    red2[w][lane + 64] = s1;
    red2[w][lane + 128] = s2;
    __syncthreads();
    if (t < 192) {
      float4 s = {0, 0, 0, 0};
#pragma unroll
      for (int ww = 0; ww < 8; ++ww) {
        const float4 u = red2[ww][t];
        s.x += u.x; s.y += u.y; s.z += u.z; s.w += u.w;
      }
      float* sp = sent + b * D + t * 4;
      atomicAdd(sp + 0, s.x);
      atomicAdd(sp + 1, s.y);
      atomicAdd(sp + 2, s.z);
      atomicAdd(sp + 3, s.w);
    }
  }
}

// ---- F3: imp slice 2  ||  q+cb (blocks 0..47)  ||  zero y (blocks 48..79) ----
__global__ __launch_bounds__(512) void k_f3(const float* __restrict__ sas,
                                            const float* __restrict__ am,
                                            const float* __restrict__ sent,
                                            const float* __restrict__ Wq,
                                            const float* __restrict__ bq,
                                            const float* __restrict__ bk,
                                            float* __restrict__ imp,
                                            float* __restrict__ qg,
                                            float* __restrict__ cbg,
                                            float* __restrict__ y) {
  __shared__ float4 red[512];
  const int bid = blockIdx.x, t = threadIdx.x;
  imp_slice(sas, am, imp, 1024 + bid, t, red);
  if (bid < 48) {
    const int h = bid >> 2;
    const int b = (bid & 3) * 8 + (t >> 6);  // wave = one b
    const int ul = t & 63;
    const int u = h * 64 + ul;
    const float* sb = sent + b * D;
    float a0 = 0.f, a1 = 0.f, a2 = 0.f, a3 = 0.f;
#pragma unroll 4
    for (int d = 0; d < D; d += 4) {
      a0 += sb[d + 0] * Wq[(size_t)(d + 0) * D + u];
      a1 += sb[d + 1] * Wq[(size_t)(d + 1) * D + u];
      a2 += sb[d + 2] * Wq[(size_t)(d + 2) * D + u];
      a3 += sb[d + 3] * Wq[(size_t)(d + 3) * D + u];
    }
    const float acc = bq[u] + ((a0 + a1) + (a2 + a3));
    qg[b * D + u] = acc;
    float v = bk[u] * acc;
#pragma unroll
    for (int o = 32; o; o >>= 1) v += __shfl_down(v, o);
    if (ul == 0) cbg[b * H + h] = v;
  } else if (bid < 80) {
    const int b = bid - 48;
    for (int i = t; i < H * D; i += 512) y[(size_t)b * H * D + i] = 0.0f;
  }
}

// ---- F4: prep/select (blocks 0..31)  ||  A (blocks 32..175) ----
__global__ __launch_bounds__(512) void k_f4(const float* __restrict__ am,
                                            const float* __restrict__ imp,
                                            const float* __restrict__ qg,
                                            const float* __restrict__ Wk,
                                            int* __restrict__ sel,
                                            float* __restrict__ out_mask,
                                            float* __restrict__ out_tome,
                                            float* __restrict__ Ag) {
  const int bid = blockIdx.x, t = threadIdx.x;
  __shared__ float v[512];
  __shared__ int sc[512];
  __shared__ float tile[64][65];
  if (bid < B) {
    const int b = bid, l = t;
    const float aml = am[b * L + l];
    float val;
    if (l == 0)
      val = INFINITY;
    else
      val = (aml > -10.0f) ? imp[b * L + l] : 0.0f;
    v[l] = val;
    __syncthreads();
    int r = 0;
    for (int tt = 0; tt < 512; ++tt) {
      const float vt = v[tt];
      r += (vt > val) || (vt == val && tt < l);
    }
    const int f = (r < KSEL) ? 1 : 0;
    sc[l] = f;
    __syncthreads();
    for (int off = 1; off < 512; off <<= 1) {
      const int add = (l >= off) ? sc[l - off] : 0;
      __syncthreads();
      sc[l] += add;
      __syncthreads();
    }
    if (f) {
      const int pos = sc[l] - 1;  // 0..254
      sel[b * KSEL + pos] = l;
      out_mask[b * 256 + pos] = aml;
    }
    if (l == 0) out_mask[b * 256 + 255] = 0.0f;
    if (l < 256) out_tome[b * 256 + l] = 1.0f;
  } else {
    const int vb = bid - B;  // 0..143
    const int h = vb / 12, dc = vb % 12;
    for (int i = t; i < 4096; i += 512) {
      const int rr = i >> 6, cc = i & 63;
      tile[rr][cc] = Wk[(size_t)(dc * 64 + rr) * D + h * 64 + cc];
    }
    __syncthreads();
    const int dl = t & 63, bl = t >> 6;
    const int d = dc * 64 + dl;
#pragma unroll
    for (int pass = 0; pass < 4; ++pass) {
      const int b = pass * 8 + bl;
      const float* qh = qg + b * D + h * 64;
      float acc = 0.f;
#pragma unroll
      for (int c = 0; c < 64; ++c) acc += tile[dl][c] * qh[c];
      Ag[((size_t)b * H + h) * D + d] = acc;
    }
  }
}

// ---- F5: logits (blocks 0..511)  ||  gather (blocks 512..2551, 4 rows each) ----
__global__ __launch_bounds__(256) void k_f5(const float* __restrict__ hs,
                                            const float* __restrict__ Ag,
                                            const float* __restrict__ cbg,
                                            const int* __restrict__ sel,
                                            float* __restrict__ lg,
                                            float* __restrict__ out_tok) {
  const int bid = blockIdx.x, t = threadIdx.x;
  __shared__ float A[H * D];  // 36 KB
  if (bid < 512) {
    const int b = bid >> 4, ch = bid & 15;
    for (int i = t; i < H * D; i += 256) A[i] = Ag[(size_t)b * H * D + i];
    __syncthreads();
    const int wave = t >> 6, lane = t & 63;
    const float* h0 = hs + (size_t)b * L * D;
    for (int li = 0; li < 8; ++li) {
      const int l = ch * 32 + li * 4 + wave;
      const float* xr = h0 + (size_t)l * D;
      float xv[12];
#pragma unroll
      for (int k = 0; k < 12; ++k) xv[k] = xr[lane + 64 * k];
#pragma unroll
      for (int h = 0; h < H; ++h) {
        float a = 0.f;
#pragma unroll
        for (int k = 0; k < 12; ++k) a += xv[k] * A[h * D + lane + 64 * k];
#pragma unroll
        for (int o = 32; o; o >>= 1) a += __shfl_down(a, o);
        if (lane == 0) lg[((size_t)b * H + h) * L + l] = (a + cbg[b * H + h]) * 0.125f;
      }
    }
  } else {
    const int vb = bid - 512;                      // 0..2039
    const int row = vb * 4 + (t >> 6);             // B*KSEL rows
    const int lane = t & 63;
    const int b = row / KSEL, p = row % KSEL;
    const int j = sel[row];
    const float4* src = reinterpret_cast<const float4*>(hs + ((size_t)b * L + j) * D);
    float4* dst = reinterpret_cast<float4*>(out_tok + ((size_t)b * 256 + p) * D);
#pragma unroll
    for (int i = 0; i < 3; ++i) dst[lane + 64 * i] = src[lane + 64 * i];
  }
}

// ---- F6: merged softmax + y ----
__global__ __launch_bounds__(768) void k_ysoft(const float* __restrict__ hs,
                                               const float* __restrict__ lg,
                                               const float* __restrict__ am,
                                               float* __restrict__ y) {
  const int b = blockIdx.x, c = blockIdx.y, t = threadIdx.x;  // c: 8 chunks of 64 l
  __shared__ float wl[H * L];
  __shared__ float Ms[H], Is[H];
  __shared__ float wn[H * 64];
  for (int i = t; i < H * L; i += 768) {
    const int l = i & (L - 1);
    const float aml = am[b * L + l];
    wl[i] = (aml < -10.0f) ? -INFINITY : lg[(size_t)b * H * L + i];
  }
  __syncthreads();
  {
    const int h = t >> 6, lane = t & 63;
    float m = -INFINITY;
#pragma unroll
    for (int k = 0; k < 8; ++k) m = fmaxf(m, wl[h * L + lane + 64 * k]);
#pragma unroll
    for (int o = 32; o; o >>= 1) m = fmaxf(m, __shfl_xor(m, o));
    float s = 0.f;
#pragma unroll
    for (int k = 0; k < 8; ++k) s += expf(wl[h * L + lane + 64 * k] - m);
#pragma unroll
    for (int o = 32; o; o >>= 1) s += __shfl_xor(s, o);
    if (lane == 0) { Ms[h] = m; Is[h] = 1.0f / s; }
  }
  __syncthreads();
  {
    const int h = t >> 6, l = t & 63;
    wn[t] = expf(wl[h * L + c * 64 + l] - Ms[h]) * Is[h];
  }
  __syncthreads();
  const float* h0 = hs + ((size_t)b * L + c * 64) * D;
  float acc[12];
#pragma unroll
  for (int h = 0; h < 12; ++h) acc[h] = 0.f;
  for (int l = 0; l < 64; ++l) {
    const float x = h0[(size_t)l * D + t];
#pragma unroll
    for (int h = 0; h < 12; ++h) acc[h] += wn[h * 64 + l] * x;
  }
#pragma unroll
  for (int h = 0; h < 12; ++h) atomicAdd(&y[((size_t)b * H + h) * D + t], acc[h]);
}

// ---- F7: ctx ----
__global__ __launch_bounds__(512) void k_ctx(const float* __restrict__ y,
                                             const float* __restrict__ Wv,
                                             const float* __restrict__ bv,
                                             float* __restrict__ ctx) {
  const int h = blockIdx.x;
  const int b = blockIdx.y * 8 + (threadIdx.x >> 6);
  const int c = threadIdx.x & 63;
  const float* yb = y + ((size_t)b * H + h) * D;
  float a0 = 0.f, a1 = 0.f, a2 = 0.f, a3 = 0.f;
#pragma unroll 4
  for (int d = 0; d < D; d += 4) {
    a0 += yb[d + 0] * Wv[(size_t)(d + 0) * D + h * 64 + c];
    a1 += yb[d + 1] * Wv[(size_t)(d + 1) * D + h * 64 + c];
    a2 += yb[d + 2] * Wv[(size_t)(d + 2) * D + h * 64 + c];
    a3 += yb[d + 3] * Wv[(size_t)(d + 3) * D + h * 64 + c];
  }
  ctx[b * D + h * 64 + c] = bv[h * 64 + c] + ((a0 + a1) + (a2 + a3));
}

// ---- F8: out ----
__global__ __launch_bounds__(512) void k_out(const float* __restrict__ ctx,
                                             const float* __restrict__ Wo,
                                             const float* __restrict__ bo,
                                             float* __restrict__ out_tok) {
  const int dc = blockIdx.x;
  const int b = blockIdx.y * 8 + (threadIdx.x >> 6);
  const int dl = threadIdx.x & 63;
  const int dd = dc * 64 + dl;
  const float* cb = ctx + b * D;
  float a0 = 0.f, a1 = 0.f, a2 = 0.f, a3 = 0.f;
#pragma unroll 4
  for (int u = 0; u < D; u += 4) {
    a0 += cb[u + 0] * Wo[(size_t)(u + 0) * D + dd];
    a1 += cb[u + 1] * Wo[(size_t)(u + 1) * D + dd];
    a2 += cb[u + 2] * Wo[(size_t)(u + 2) * D + dd];
    a3 += cb[u + 3] * Wo[(size_t)(u + 3) * D + dd];
  }
  out_tok[((size_t)b * 256 + 255) * D + dd] = bo[dd] + ((a0 + a1) + (a2 + a3));
}

extern "C" void kernel_launch(void* const* d_in, const int* in_sizes, int n_in,
                              void* d_out, int out_size, void* d_ws, size_t ws_size,
                              hipStream_t stream) {
  const float* hs = (const float*)d_in[0];
  const float* am = (const float*)d_in[1];
  const float* sas = (const float*)d_in[2];
  const float* Wq = (const float*)d_in[3];
  const float* bq = (const float*)d_in[4];
  const float* Wk = (const float*)d_in[5];
  const float* bk = (const float*)d_in[6];
  const float* Wv = (const float*)d_in[7];
  const float* bv = (const float*)d_in[8];
  const float* Wo = (const float*)d_in[9];
  const float* bo = (const float*)d_in[10];

  float* out_tok = (float*)d_out;                   // [B,256,D]
  float* out_mask = out_tok + (size_t)B * 256 * D;  // [B,1,1,256]
  float* out_tome = out_mask + (size_t)B * 256;     // [B,256,1]

  char* ws = (char*)d_ws;
  float* imp = (float*)(ws + OFF_IMP);
  float* att = (float*)(ws + OFF_ATT);
  float* sent = (float*)(ws + OFF_SENT);
  float* qg = (float*)(ws + OFF_Q);
  float* cbg = (float*)(ws + OFF_CB);
  float* Ag = (float*)(ws + OFF_A);
  float* lg = (float*)(ws + OFF_LG);
  int* sel = (int*)(ws + OFF_SEL);
  float* yg = (float*)(ws + OFF_Y);
  float* ctx = (float*)(ws + OFF_CTX);

  hipMemsetAsync(d_ws, 0, MEMSET_BYTES, stream);

  k_f1<<<512, 512, 0, stream>>>(sas, am, imp, att, sent);
  k_f2<<<512, 512, 0, stream>>>(sas, am, hs, att, imp, sent);
  k_f3<<<512, 512, 0, stream>>>(sas, am, sent, Wq, bq, bk, imp, qg, cbg, yg);
  k_f4<<<176, 512, 0, stream>>>(am, imp, qg, Wk, sel, out_mask, out_tome, Ag);
  k_f5<<<2552, 256, 0, stream>>>(hs, Ag, cbg, sel, lg, out_tok);
  k_ysoft<<<dim3(B, 8), 768, 0, stream>>>(hs, lg, am, yg);
  k_ctx<<<dim3(12, 4), 512, 0, stream>>>(yg, Wv, bv, ctx);
  k_out<<<dim3(12, 4), 512, 0, stream>>>(ctx, Wo, bo, out_tok);
}